// Round 1
// baseline (297.156 us; speedup 1.0000x reference)
//
#include <hip/hip_runtime.h>
#include <stdint.h>

typedef float f32x4 __attribute__((ext_vector_type(4)));
typedef short s16x8 __attribute__((ext_vector_type(8)));

typedef const __attribute__((address_space(1))) uint32_t* gas_t;
typedef __attribute__((address_space(3))) uint32_t* las_t;

__device__ __forceinline__ void gload16(const void* g, void* l) {
  __builtin_amdgcn_global_load_lds((gas_t)g, (las_t)l, 16, 0, 0);
}

__device__ __forceinline__ short f2bf(float f) {
  union { float f; uint32_t u; } v; v.f = f;
  uint32_t r = v.u + 0x7fffu + ((v.u >> 16) & 1u);
  return (short)(r >> 16);
}

#define MFMA16(a,b,c) __builtin_amdgcn_mfma_f32_16x16x32_bf16((a),(b),(c),0,0,0)

// ---------------- mask handling (dtype-robust) ----------------
__global__ void mask_detect_kernel(const uint32_t* __restrict__ m, uint32_t* __restrict__ flag) {
  uint32_t v = m[blockIdx.x * 256 + threadIdx.x];   // first 8KB, safe for bool8 or int32
  if (v > 1u) atomicOr(flag, 1u);
}

__global__ void mask_bias_kernel(const uint32_t* __restrict__ m, const uint32_t* __restrict__ flag,
                                 float* __restrict__ mb) {
  int j = blockIdx.x * 256 + threadIdx.x;           // 8192
  uint32_t f = *flag;
  uint32_t v = f ? (uint32_t)((const uint8_t*)m)[j] : m[j];
  mb[j] = v ? -1e30f : 0.0f;
}

// ---------------- weight transpose f32 -> bf16 (WT[C][R]) ----------------
__global__ __launch_bounds__(256) void transpose_kernel(const float* __restrict__ W,
    short* __restrict__ WT, int R, int C) {
  __shared__ float tile[32][33];
  const int c0 = blockIdx.x * 32, r0 = blockIdx.y * 32;
  const int tx = threadIdx.x & 31, ty = threadIdx.x >> 5;
#pragma unroll
  for (int i = 0; i < 32; i += 8)
    tile[ty + i][tx] = W[(size_t)(r0 + ty + i) * C + c0 + tx];
  __syncthreads();
#pragma unroll
  for (int i = 0; i < 32; i += 8)
    WT[(size_t)(c0 + ty + i) * R + r0 + tx] = f2bf(tile[tx][ty + i]);
}

// ---------------- layernorm f32 -> bf16 ----------------
__global__ __launch_bounds__(64) void ln_kernel(const float* __restrict__ keys,
    const float* __restrict__ values, const float* __restrict__ g0, const float* __restrict__ b0,
    const float* __restrict__ g1, const float* __restrict__ b1,
    short* __restrict__ kn, short* __restrict__ vn) {
  const int row = blockIdx.x, sel = blockIdx.y, lane = threadIdx.x;
  const float* x = (sel ? values : keys) + (size_t)row * 512;
  const float* ga = sel ? g1 : g0;
  const float* be = sel ? b1 : b0;
  short* out = (sel ? vn : kn) + (size_t)row * 512;
  float4 a = ((const float4*)x)[lane * 2];
  float4 c = ((const float4*)x)[lane * 2 + 1];
  float s = a.x + a.y + a.z + a.w + c.x + c.y + c.z + c.w;
  float sq = a.x*a.x + a.y*a.y + a.z*a.z + a.w*a.w + c.x*c.x + c.y*c.y + c.z*c.z + c.w*c.w;
#pragma unroll
  for (int m = 1; m < 64; m <<= 1) { s += __shfl_xor(s, m); sq += __shfl_xor(sq, m); }
  float mu = s * (1.0f / 512.0f);
  float var = sq * (1.0f / 512.0f) - mu * mu;
  float rs = rsqrtf(var + 1e-5f);
  float xs[8] = {a.x, a.y, a.z, a.w, c.x, c.y, c.z, c.w};
  s16x8 o;
#pragma unroll
  for (int j = 0; j < 8; j++)
    o[j] = f2bf((xs[j] - mu) * rs * ga[lane * 8 + j] + be[lane * 8 + j]);
  *(s16x8*)(out + lane * 8) = o;
}

// ---------------- shared 128x128 GEMM core, K=512, BK=64 ----------------
// A[M][512] bf16 row-major; BT[N][512] bf16 (i.e. B transposed). acc[4][4] per wave (64x64).
__device__ __forceinline__ void gemm_core(const short* __restrict__ A,
                                          const short* __restrict__ BT,
                                          int row0, int col0,
                                          short* ldsA, short* ldsB,
                                          f32x4 acc[4][4]) {
  const int t = threadIdx.x;
  const int lane = t & 63, w = t >> 6;
  const int wr = w >> 1, wc = w & 1;
  const int l15 = lane & 15, l4 = lane >> 4;
#pragma unroll
  for (int mi = 0; mi < 4; mi++)
#pragma unroll
    for (int ni = 0; ni < 4; ni++) acc[mi][ni] = (f32x4){0.f, 0.f, 0.f, 0.f};

  for (int k0 = 0; k0 < 512; k0 += 64) {
    __syncthreads();
#pragma unroll
    for (int i = 0; i < 4; i++) {
      int q = i * 256 + t;               // chunk id: row=q>>3 (0..127), ch=q&7
      int row = q >> 3, ch = q & 7;
      int chs = ch ^ (row & 7);          // pre-swizzled source -> linear LDS is swizzled
      gload16(A + (size_t)(row0 + row) * 512 + k0 + chs * 8, ldsA + (i * 256 + w * 64) * 8);
      gload16(BT + (size_t)(col0 + row) * 512 + k0 + chs * 8, ldsB + (i * 256 + w * 64) * 8);
    }
    __syncthreads();
#pragma unroll
    for (int kk = 0; kk < 2; kk++) {
      s16x8 af[4], bf[4];
#pragma unroll
      for (int mi = 0; mi < 4; mi++) {
        int row = wr * 64 + mi * 16 + l15;
        int ch = (kk * 4 + l4) ^ (row & 7);
        af[mi] = *(const s16x8*)(ldsA + row * 64 + ch * 8);
      }
#pragma unroll
      for (int ni = 0; ni < 4; ni++) {
        int row = wc * 64 + ni * 16 + l15;
        int ch = (kk * 4 + l4) ^ (row & 7);
        bf[ni] = *(const s16x8*)(ldsB + row * 64 + ch * 8);
      }
#pragma unroll
      for (int mi = 0; mi < 4; mi++)
#pragma unroll
        for (int ni = 0; ni < 4; ni++)
          acc[mi][ni] = MFMA16(af[mi], bf[ni], acc[mi][ni]);
    }
  }
}

// GEMM1: kn @ W_qk -> Q,K in [B,H,N,64] bf16 with clip(+-5)
__global__ __launch_bounds__(256) void gemm_qk_kernel(const short* __restrict__ kn,
    const short* __restrict__ WqkT, short* __restrict__ Qg, short* __restrict__ Kg) {
  __shared__ short lds[2][128 * 64];
  f32x4 acc[4][4];
  const int bm = blockIdx.x, bn = blockIdx.y;
  gemm_core(kn, WqkT, bm * 128, bn * 128, lds[0], lds[1], acc);
  const int t = threadIdx.x, lane = t & 63, w = t >> 6, wr = w >> 1, wc = w & 1;
  const int l15 = lane & 15, l4 = lane >> 4;
#pragma unroll
  for (int mi = 0; mi < 4; mi++)
#pragma unroll
    for (int ni = 0; ni < 4; ni++) {
      int col = bn * 128 + wc * 64 + ni * 16 + l15;
      short* dst = (col < 512) ? Qg : Kg;
      int c = col & 511, h = c >> 6, d = c & 63;
#pragma unroll
      for (int r = 0; r < 4; r++) {
        int row = bm * 128 + wr * 64 + mi * 16 + l4 * 4 + r;
        int b = row >> 12, n = row & 4095;
        float v = acc[mi][ni][r];
        v = fminf(fmaxf(v, -5.0f), 5.0f);
        dst[((size_t)((b * 8 + h) * 4096 + n) << 6) + d] = f2bf(v);
      }
    }
}

// GEMM2: vn @ W_v -> VT [B,H,64,N] bf16 (transposed via swizzled LDS)
__global__ __launch_bounds__(256) void gemm_v_kernel(const short* __restrict__ vn,
    const short* __restrict__ WvT, short* __restrict__ VTg) {
  __shared__ short lds[2][128 * 64];
  f32x4 acc[4][4];
  const int bm = blockIdx.x, bn = blockIdx.y;
  gemm_core(vn, WvT, bm * 128, bn * 128, lds[0], lds[1], acc);
  __syncthreads();
  short* T = (short*)lds;  // 128 c-rows x 128 n, 16-chunk XOR swizzle per row
  const int t = threadIdx.x, lane = t & 63, w = t >> 6, wr = w >> 1, wc = w & 1;
  const int l15 = lane & 15, l4 = lane >> 4;
#pragma unroll
  for (int mi = 0; mi < 4; mi++)
#pragma unroll
    for (int ni = 0; ni < 4; ni++) {
      int c_loc = wc * 64 + ni * 16 + l15;
#pragma unroll
      for (int r = 0; r < 4; r++) {
        int n_loc = wr * 64 + mi * 16 + l4 * 4 + r;
        T[c_loc * 128 + (((n_loc >> 3) ^ (c_loc & 15)) << 3) + (n_loc & 7)] = f2bf(acc[mi][ni][r]);
      }
    }
  __syncthreads();
#pragma unroll
  for (int j = 0; j < 8; j++) {
    int c_loc = j * 16 + (t >> 4);
    int nch = t & 15;
    s16x8 v = *(const s16x8*)(T + c_loc * 128 + ((nch ^ (c_loc & 15)) << 3));
    int cg = bn * 128 + c_loc, h = cg >> 6, d = cg & 63;
    int rg = bm * 128 + nch * 8, b = rg >> 12;
    *(s16x8*)(VTg + (size_t)((b * 8 + h) * 64 + d) * 4096 + (rg & 4095)) = v;
  }
}

// GEMM3: O @ W_out + b -> f32 out
__global__ __launch_bounds__(256) void gemm_out_kernel(const short* __restrict__ O,
    const short* __restrict__ WoutT, const float* __restrict__ bias, float* __restrict__ out) {
  __shared__ short lds[2][128 * 64];
  f32x4 acc[4][4];
  const int bm = blockIdx.x, bn = blockIdx.y;
  gemm_core(O, WoutT, bm * 128, bn * 128, lds[0], lds[1], acc);
  const int t = threadIdx.x, lane = t & 63, w = t >> 6, wr = w >> 1, wc = w & 1;
  const int l15 = lane & 15, l4 = lane >> 4;
#pragma unroll
  for (int ni = 0; ni < 4; ni++) {
    int col = bn * 128 + wc * 64 + ni * 16 + l15;
    float bv = bias[col];
#pragma unroll
    for (int mi = 0; mi < 4; mi++)
#pragma unroll
      for (int r = 0; r < 4; r++) {
        int row = bm * 128 + wr * 64 + mi * 16 + l4 * 4 + r;
        out[(size_t)row * 512 + col] = acc[mi][ni][r] + bv;
      }
  }
}

// ---------------- flash attention ----------------
// grid (N/128, B*H); 4 waves x 2 strips of 16 q-rows. K,VT staged in swizzled LDS.
__global__ __launch_bounds__(256, 2) void attn_kernel(const short* __restrict__ Qg,
    const short* __restrict__ Kg, const short* __restrict__ VTg,
    const float* __restrict__ mb, short* __restrict__ O) {
  __shared__ short Kt[64 * 64];
  __shared__ short Vt[64 * 64];
  __shared__ short Pw[4][2][16 * 64];
  __shared__ float mbs[64];
  const int qb = blockIdx.x, bh = blockIdx.y;
  const int b = bh >> 3, h = bh & 7;
  const int t = threadIdx.x, lane = t & 63, w = t >> 6;
  const int l15 = lane & 15, l4 = lane >> 4;
  const short* Qp = Qg + (size_t)bh * 4096 * 64;
  const short* Kp = Kg + (size_t)bh * 4096 * 64;
  const short* Vp = VTg + (size_t)bh * 64 * 4096;

  s16x8 qa[2][2];
#pragma unroll
  for (int s = 0; s < 2; s++)
#pragma unroll
    for (int kk = 0; kk < 2; kk++)
      qa[s][kk] = *(const s16x8*)(Qp + (size_t)(qb * 128 + w * 32 + s * 16 + l15) * 64 + kk * 32 + l4 * 8);

  f32x4 oacc[2][4];
  float mrow[2][4], lrow[2][4];
#pragma unroll
  for (int s = 0; s < 2; s++) {
#pragma unroll
    for (int ng = 0; ng < 4; ng++) oacc[s][ng] = (f32x4){0.f, 0.f, 0.f, 0.f};
#pragma unroll
    for (int r = 0; r < 4; r++) { mrow[s][r] = -1e30f; lrow[s][r] = 0.0f; }
  }

  for (int kt = 0; kt < 64; kt++) {
    __syncthreads();
#pragma unroll
    for (int i = 0; i < 2; i++) {
      int q = i * 256 + t;
      int row = q >> 3, ch = q & 7, chs = ch ^ (row & 7);
      gload16(Kp + (size_t)(kt * 64 + row) * 64 + chs * 8, Kt + (i * 256 + w * 64) * 8);
      gload16(Vp + (size_t)row * 4096 + kt * 64 + chs * 8, Vt + (i * 256 + w * 64) * 8);
    }
    if (w == 0) mbs[lane] = mb[b * 4096 + kt * 64 + lane];
    __syncthreads();

    // S = Q K^T  (B-frags from Kt)
    s16x8 kf[4][2];
#pragma unroll
    for (int ng = 0; ng < 4; ng++) {
      int row = ng * 16 + l15;
#pragma unroll
      for (int kk = 0; kk < 2; kk++) {
        int ch = (kk * 4 + l4) ^ (row & 7);
        kf[ng][kk] = *(const s16x8*)(Kt + row * 64 + ch * 8);
      }
    }
    float sv[2][4][4];
#pragma unroll
    for (int s = 0; s < 2; s++)
#pragma unroll
      for (int ng = 0; ng < 4; ng++) {
        f32x4 sa = (f32x4){0.f, 0.f, 0.f, 0.f};
#pragma unroll
        for (int kk = 0; kk < 2; kk++) sa = MFMA16(qa[s][kk], kf[ng][kk], sa);
#pragma unroll
        for (int r = 0; r < 4; r++) sv[s][ng][r] = sa[r] * 0.125f + mbs[ng * 16 + l15];
      }

    // online softmax per strip; P -> swizzled per-wave LDS
#pragma unroll
    for (int s = 0; s < 2; s++) {
      float tm[4], alpha[4], ps[4];
#pragma unroll
      for (int r = 0; r < 4; r++)
        tm[r] = fmaxf(fmaxf(sv[s][0][r], sv[s][1][r]), fmaxf(sv[s][2][r], sv[s][3][r]));
#pragma unroll
      for (int m = 1; m < 16; m <<= 1)
#pragma unroll
        for (int r = 0; r < 4; r++) tm[r] = fmaxf(tm[r], __shfl_xor(tm[r], m));
#pragma unroll
      for (int r = 0; r < 4; r++) {
        float mn = fmaxf(mrow[s][r], tm[r]);
        alpha[r] = __expf(mrow[s][r] - mn);
        mrow[s][r] = mn;
        ps[r] = 0.0f;
      }
#pragma unroll
      for (int ng = 0; ng < 4; ng++)
#pragma unroll
        for (int r = 0; r < 4; r++) {
          float p = __expf(sv[s][ng][r] - mrow[s][r]);
          ps[r] += p;
          int prow = l4 * 4 + r, key = ng * 16 + l15;
          Pw[w][s][prow * 64 + (((key >> 3) ^ (prow & 7)) << 3) + (key & 7)] = f2bf(p);
        }
#pragma unroll
      for (int m = 1; m < 16; m <<= 1)
#pragma unroll
        for (int r = 0; r < 4; r++) ps[r] += __shfl_xor(ps[r], m);
#pragma unroll
      for (int r = 0; r < 4; r++) lrow[s][r] = lrow[s][r] * alpha[r] + ps[r];
#pragma unroll
      for (int ng = 0; ng < 4; ng++)
#pragma unroll
        for (int r = 0; r < 4; r++) oacc[s][ng][r] *= alpha[r];
    }

    // O += P V  (A-frags from Pw via LDS transpose, B-frags from Vt)
    s16x8 vf[4][2];
#pragma unroll
    for (int ng = 0; ng < 4; ng++) {
      int row = ng * 16 + l15;
#pragma unroll
      for (int kk = 0; kk < 2; kk++) {
        int ch = (kk * 4 + l4) ^ (row & 7);
        vf[ng][kk] = *(const s16x8*)(Vt + row * 64 + ch * 8);
      }
    }
#pragma unroll
    for (int s = 0; s < 2; s++) {
      s16x8 pf[2];
#pragma unroll
      for (int kk = 0; kk < 2; kk++) {
        int ch = (kk * 4 + l4) ^ (l15 & 7);
        pf[kk] = *(const s16x8*)(&Pw[w][s][0] + l15 * 64 + ch * 8);
      }
#pragma unroll
      for (int ng = 0; ng < 4; ng++)
#pragma unroll
        for (int kk = 0; kk < 2; kk++)
          oacc[s][ng] = MFMA16(pf[kk], vf[ng][kk], oacc[s][ng]);
    }
  }

  // epilogue: O[b,n,h*64+d] bf16
#pragma unroll
  for (int s = 0; s < 2; s++)
#pragma unroll
    for (int ng = 0; ng < 4; ng++)
#pragma unroll
      for (int r = 0; r < 4; r++) {
        int n = qb * 128 + w * 32 + s * 16 + l4 * 4 + r;
        int d = ng * 16 + l15;
        float v = oacc[s][ng][r] / lrow[s][r];
        O[(size_t)(b * 4096 + n) * 512 + h * 64 + d] = f2bf(v);
      }
}

extern "C" void kernel_launch(void* const* d_in, const int* in_sizes, int n_in,
                              void* d_out, int out_size, void* d_ws, size_t ws_size,
                              hipStream_t stream) {
  const float* keys     = (const float*)d_in[0];
  const float* values   = (const float*)d_in[1];
  const uint32_t* maskp = (const uint32_t*)d_in[2];
  const float* qk_gamma = (const float*)d_in[3];
  const float* qk_beta  = (const float*)d_in[4];
  const float* v_gamma  = (const float*)d_in[5];
  const float* v_beta   = (const float*)d_in[6];
  const float* W_qk     = (const float*)d_in[7];
  const float* W_v      = (const float*)d_in[8];
  const float* W_out    = (const float*)d_in[9];
  const float* b_out    = (const float*)d_in[10];
  float* out = (float*)d_out;
  char* ws = (char*)d_ws;
  const size_t MB = 1u << 20;
  short* kn    = (short*)(ws);
  short* vn    = (short*)(ws + 8 * MB);
  short* Qg    = (short*)(ws + 16 * MB);
  short* Kg    = (short*)(ws + 24 * MB);
  short* VTg   = (short*)(ws + 32 * MB);
  short* O     = (short*)(ws + 40 * MB);
  short* WqkT  = (short*)(ws + 48 * MB);
  short* WvT   = (short*)(ws + 49 * MB);
  short* WoutT = (short*)(ws + 49 * MB + 512 * 1024);
  float* mb    = (float*)(ws + 50 * MB);
  uint32_t* flag = (uint32_t*)(ws + 50 * MB + 32 * 1024);

  hipMemsetAsync(flag, 0, 4, stream);
  mask_detect_kernel<<<8, 256, 0, stream>>>(maskp, flag);
  mask_bias_kernel<<<32, 256, 0, stream>>>(maskp, flag, mb);
  transpose_kernel<<<dim3(32, 16), 256, 0, stream>>>(W_qk, WqkT, 512, 1024);
  transpose_kernel<<<dim3(16, 16), 256, 0, stream>>>(W_v, WvT, 512, 512);
  transpose_kernel<<<dim3(16, 16), 256, 0, stream>>>(W_out, WoutT, 512, 512);
  ln_kernel<<<dim3(8192, 2), 64, 0, stream>>>(keys, values, qk_gamma, qk_beta, v_gamma, v_beta, kn, vn);
  gemm_qk_kernel<<<dim3(64, 8), 256, 0, stream>>>(kn, WqkT, Qg, Kg);
  gemm_v_kernel<<<dim3(64, 4), 256, 0, stream>>>(vn, WvT, VTg);
  attn_kernel<<<dim3(32, 16), 256, 0, stream>>>(Qg, Kg, VTg, mb, O);
  gemm_out_kernel<<<dim3(64, 4), 256, 0, stream>>>(O, WoutT, b_out, out);
}

// Round 2
// 276.178 us; speedup vs baseline: 1.0760x; 1.0760x over previous
//
#include <hip/hip_runtime.h>
#include <stdint.h>

typedef float f32x4 __attribute__((ext_vector_type(4)));
typedef short s16x8 __attribute__((ext_vector_type(8)));

typedef const __attribute__((address_space(1))) uint32_t* gas_t;
typedef __attribute__((address_space(3))) uint32_t* las_t;

__device__ __forceinline__ void gload16(const void* g, void* l) {
  __builtin_amdgcn_global_load_lds((gas_t)g, (las_t)l, 16, 0, 0);
}

__device__ __forceinline__ short f2bf(float f) {
  union { float f; uint32_t u; } v; v.f = f;
  uint32_t r = v.u + 0x7fffu + ((v.u >> 16) & 1u);
  return (short)(r >> 16);
}

#define MFMA16(a,b,c) __builtin_amdgcn_mfma_f32_16x16x32_bf16((a),(b),(c),0,0,0)

// ---------------- mask handling (dtype-robust) ----------------
__global__ void mask_detect_kernel(const uint32_t* __restrict__ m, uint32_t* __restrict__ flag) {
  uint32_t v = m[blockIdx.x * 256 + threadIdx.x];   // first 8KB, safe for bool8 or int32
  if (v > 1u) atomicOr(flag, 1u);
}

__global__ void mask_bias_kernel(const uint32_t* __restrict__ m, const uint32_t* __restrict__ flag,
                                 float* __restrict__ mb) {
  int j = blockIdx.x * 256 + threadIdx.x;           // 8192
  uint32_t f = *flag;
  uint32_t v = f ? (uint32_t)((const uint8_t*)m)[j] : m[j];
  mb[j] = v ? -1e30f : 0.0f;
}

// ---------------- weight transpose f32 -> bf16 (WT[C][R]) ----------------
__global__ __launch_bounds__(256) void transpose_kernel(const float* __restrict__ W,
    short* __restrict__ WT, int R, int C) {
  __shared__ float tile[32][33];
  const int c0 = blockIdx.x * 32, r0 = blockIdx.y * 32;
  const int tx = threadIdx.x & 31, ty = threadIdx.x >> 5;
#pragma unroll
  for (int i = 0; i < 32; i += 8)
    tile[ty + i][tx] = W[(size_t)(r0 + ty + i) * C + c0 + tx];
  __syncthreads();
#pragma unroll
  for (int i = 0; i < 32; i += 8)
    WT[(size_t)(c0 + ty + i) * R + r0 + tx] = f2bf(tile[tx][ty + i]);
}

// ---------------- layernorm f32 -> bf16 ----------------
__global__ __launch_bounds__(64) void ln_kernel(const float* __restrict__ keys,
    const float* __restrict__ values, const float* __restrict__ g0, const float* __restrict__ b0,
    const float* __restrict__ g1, const float* __restrict__ b1,
    short* __restrict__ kn, short* __restrict__ vn) {
  const int row = blockIdx.x, sel = blockIdx.y, lane = threadIdx.x;
  const float* x = (sel ? values : keys) + (size_t)row * 512;
  const float* ga = sel ? g1 : g0;
  const float* be = sel ? b1 : b0;
  short* out = (sel ? vn : kn) + (size_t)row * 512;
  float4 a = ((const float4*)x)[lane * 2];
  float4 c = ((const float4*)x)[lane * 2 + 1];
  float s = a.x + a.y + a.z + a.w + c.x + c.y + c.z + c.w;
  float sq = a.x*a.x + a.y*a.y + a.z*a.z + a.w*a.w + c.x*c.x + c.y*c.y + c.z*c.z + c.w*c.w;
#pragma unroll
  for (int m = 1; m < 64; m <<= 1) { s += __shfl_xor(s, m); sq += __shfl_xor(sq, m); }
  float mu = s * (1.0f / 512.0f);
  float var = sq * (1.0f / 512.0f) - mu * mu;
  float rs = rsqrtf(var + 1e-5f);
  float xs[8] = {a.x, a.y, a.z, a.w, c.x, c.y, c.z, c.w};
  s16x8 o;
#pragma unroll
  for (int j = 0; j < 8; j++)
    o[j] = f2bf((xs[j] - mu) * rs * ga[lane * 8 + j] + be[lane * 8 + j]);
  *(s16x8*)(out + lane * 8) = o;
}

// ---------------- shared 128x128 GEMM core, K=512, BK=64 ----------------
__device__ __forceinline__ void gemm_core(const short* __restrict__ A,
                                          const short* __restrict__ BT,
                                          int row0, int col0,
                                          short* ldsA, short* ldsB,
                                          f32x4 acc[4][4]) {
  const int t = threadIdx.x;
  const int lane = t & 63, w = t >> 6;
  const int wr = w >> 1, wc = w & 1;
  const int l15 = lane & 15, l4 = lane >> 4;
#pragma unroll
  for (int mi = 0; mi < 4; mi++)
#pragma unroll
    for (int ni = 0; ni < 4; ni++) acc[mi][ni] = (f32x4){0.f, 0.f, 0.f, 0.f};

  for (int k0 = 0; k0 < 512; k0 += 64) {
    __syncthreads();
#pragma unroll
    for (int i = 0; i < 4; i++) {
      int q = i * 256 + t;               // chunk id: row=q>>3 (0..127), ch=q&7
      int row = q >> 3, ch = q & 7;
      int chs = ch ^ (row & 7);          // pre-swizzled source -> linear LDS is swizzled
      gload16(A + (size_t)(row0 + row) * 512 + k0 + chs * 8, ldsA + (i * 256 + w * 64) * 8);
      gload16(BT + (size_t)(col0 + row) * 512 + k0 + chs * 8, ldsB + (i * 256 + w * 64) * 8);
    }
    __syncthreads();
#pragma unroll
    for (int kk = 0; kk < 2; kk++) {
      s16x8 af[4], bf[4];
#pragma unroll
      for (int mi = 0; mi < 4; mi++) {
        int row = wr * 64 + mi * 16 + l15;
        int ch = (kk * 4 + l4) ^ (row & 7);
        af[mi] = *(const s16x8*)(ldsA + row * 64 + ch * 8);
      }
#pragma unroll
      for (int ni = 0; ni < 4; ni++) {
        int row = wc * 64 + ni * 16 + l15;
        int ch = (kk * 4 + l4) ^ (row & 7);
        bf[ni] = *(const s16x8*)(ldsB + row * 64 + ch * 8);
      }
#pragma unroll
      for (int mi = 0; mi < 4; mi++)
#pragma unroll
        for (int ni = 0; ni < 4; ni++)
          acc[mi][ni] = MFMA16(af[mi], bf[ni], acc[mi][ni]);
    }
  }
}

// GEMM1: kn @ W_qk -> Q,K in [B,H,N,64] bf16 with clip(+-5)
__global__ __launch_bounds__(256) void gemm_qk_kernel(const short* __restrict__ kn,
    const short* __restrict__ WqkT, short* __restrict__ Qg, short* __restrict__ Kg) {
  __shared__ short lds[2][128 * 64];
  f32x4 acc[4][4];
  const int bm = blockIdx.x, bn = blockIdx.y;
  gemm_core(kn, WqkT, bm * 128, bn * 128, lds[0], lds[1], acc);
  const int t = threadIdx.x, lane = t & 63, w = t >> 6, wr = w >> 1, wc = w & 1;
  const int l15 = lane & 15, l4 = lane >> 4;
#pragma unroll
  for (int mi = 0; mi < 4; mi++)
#pragma unroll
    for (int ni = 0; ni < 4; ni++) {
      int col = bn * 128 + wc * 64 + ni * 16 + l15;
      short* dst = (col < 512) ? Qg : Kg;
      int c = col & 511, h = c >> 6, d = c & 63;
#pragma unroll
      for (int r = 0; r < 4; r++) {
        int row = bm * 128 + wr * 64 + mi * 16 + l4 * 4 + r;
        int b = row >> 12, n = row & 4095;
        float v = acc[mi][ni][r];
        v = fminf(fmaxf(v, -5.0f), 5.0f);
        dst[((size_t)((b * 8 + h) * 4096 + n) << 6) + d] = f2bf(v);
      }
    }
}

// GEMM2: vn @ W_v -> VT [B,H,64,N] bf16 (transposed via swizzled LDS)
__global__ __launch_bounds__(256) void gemm_v_kernel(const short* __restrict__ vn,
    const short* __restrict__ WvT, short* __restrict__ VTg) {
  __shared__ short lds[2][128 * 64];
  f32x4 acc[4][4];
  const int bm = blockIdx.x, bn = blockIdx.y;
  gemm_core(vn, WvT, bm * 128, bn * 128, lds[0], lds[1], acc);
  __syncthreads();
  short* T = (short*)lds;  // 128 c-rows x 128 n, 16-chunk XOR swizzle per row
  const int t = threadIdx.x, lane = t & 63, w = t >> 6, wr = w >> 1, wc = w & 1;
  const int l15 = lane & 15, l4 = lane >> 4;
#pragma unroll
  for (int mi = 0; mi < 4; mi++)
#pragma unroll
    for (int ni = 0; ni < 4; ni++) {
      int c_loc = wc * 64 + ni * 16 + l15;
#pragma unroll
      for (int r = 0; r < 4; r++) {
        int n_loc = wr * 64 + mi * 16 + l4 * 4 + r;
        T[c_loc * 128 + (((n_loc >> 3) ^ (c_loc & 15)) << 3) + (n_loc & 7)] = f2bf(acc[mi][ni][r]);
      }
    }
  __syncthreads();
#pragma unroll
  for (int j = 0; j < 8; j++) {
    int c_loc = j * 16 + (t >> 4);
    int nch = t & 15;
    s16x8 v = *(const s16x8*)(T + c_loc * 128 + ((nch ^ (c_loc & 15)) << 3));
    int cg = bn * 128 + c_loc, h = cg >> 6, d = cg & 63;
    int rg = bm * 128 + nch * 8, b = rg >> 12;
    *(s16x8*)(VTg + (size_t)((b * 8 + h) * 64 + d) * 4096 + (rg & 4095)) = v;
  }
}

// GEMM3: O @ W_out + b -> f32 out
__global__ __launch_bounds__(256) void gemm_out_kernel(const short* __restrict__ O,
    const short* __restrict__ WoutT, const float* __restrict__ bias, float* __restrict__ out) {
  __shared__ short lds[2][128 * 64];
  f32x4 acc[4][4];
  const int bm = blockIdx.x, bn = blockIdx.y;
  gemm_core(O, WoutT, bm * 128, bn * 128, lds[0], lds[1], acc);
  const int t = threadIdx.x, lane = t & 63, w = t >> 6, wr = w >> 1, wc = w & 1;
  const int l15 = lane & 15, l4 = lane >> 4;
#pragma unroll
  for (int ni = 0; ni < 4; ni++) {
    int col = bn * 128 + wc * 64 + ni * 16 + l15;
    float bv = bias[col];
#pragma unroll
    for (int mi = 0; mi < 4; mi++)
#pragma unroll
      for (int r = 0; r < 4; r++) {
        int row = bm * 128 + wr * 64 + mi * 16 + l4 * 4 + r;
        out[(size_t)row * 512 + col] = acc[mi][ni][r] + bv;
      }
  }
}

// ---------------- flash attention (R2: dbuf staging, BQ=64, XCD swizzle) ----
// grid (64,16): remapped so each XCD owns 2 bh (K/V L2-resident).
// 4 waves x 16 q-rows; KV tile 64, double-buffered; one barrier per tile.
__global__ __launch_bounds__(256, 4) void attn_kernel(const short* __restrict__ Qg,
    const short* __restrict__ Kg, const short* __restrict__ VTg,
    const float* __restrict__ mb, short* __restrict__ O) {
  __shared__ short Kt[2][64 * 64];
  __shared__ short Vt[2][64 * 64];
  __shared__ short Pw[4][16 * 64];

  const int flat = blockIdx.x + (int)gridDim.x * blockIdx.y;  // 0..1023
  const int bh = (flat & 7) * 2 + ((flat >> 3) & 1);
  const int qb = flat >> 4;                                    // 0..63
  const int b = bh >> 3, h = bh & 7;
  const int t = threadIdx.x, lane = t & 63, w = t >> 6;
  const int l15 = lane & 15, l4 = lane >> 4;
  const short* Qp = Qg + (size_t)bh * 4096 * 64;
  const short* Kp = Kg + (size_t)bh * 4096 * 64;
  const short* Vp = VTg + (size_t)bh * 64 * 4096;
  const float* mbp = mb + b * 4096;

  // Q fragment: rows qb*64 + w*16 + l15
  s16x8 qa[2];
#pragma unroll
  for (int kk = 0; kk < 2; kk++)
    qa[kk] = *(const s16x8*)(Qp + (size_t)(qb * 64 + w * 16 + l15) * 64 + kk * 32 + l4 * 8);

  f32x4 oacc[4];
  float mrow[4], lrow[4];
#pragma unroll
  for (int ng = 0; ng < 4; ng++) oacc[ng] = (f32x4){0.f, 0.f, 0.f, 0.f};
#pragma unroll
  for (int r = 0; r < 4; r++) { mrow[r] = -1e30f; lrow[r] = 0.0f; }

  const float SCL = 0.125f * 1.44269504088896f;  // log2 domain

  // stage K/V tile kt into buffer bufi (pre-swizzled source -> linear LDS)
  auto STAGE = [&](int bufi, int kt) {
#pragma unroll
    for (int i = 0; i < 2; i++) {
      int q = i * 256 + t;
      int row = q >> 3, ch = q & 7, chs = ch ^ (row & 7);
      gload16(Kp + (size_t)(kt * 64 + row) * 64 + chs * 8, Kt[bufi] + (i * 256 + w * 64) * 8);
      gload16(Vp + (size_t)row * 4096 + kt * 64 + chs * 8, Vt[bufi] + (i * 256 + w * 64) * 8);
    }
  };

  STAGE(0, 0);
  __syncthreads();

  for (int kt = 0; kt < 64; kt++) {
    const int cur = kt & 1;
    if (kt < 63) STAGE(cur ^ 1, kt + 1);   // overlaps with compute below

    // mask bias (log2-domain safe: -1e30)
    float mreg[4];
#pragma unroll
    for (int ng = 0; ng < 4; ng++) mreg[ng] = mbp[kt * 64 + ng * 16 + l15];

    // S = Q K^T
    s16x8 kf[4][2];
#pragma unroll
    for (int ng = 0; ng < 4; ng++) {
      int row = ng * 16 + l15;
#pragma unroll
      for (int kk = 0; kk < 2; kk++) {
        int ch = (kk * 4 + l4) ^ (row & 7);
        kf[ng][kk] = *(const s16x8*)(Kt[cur] + row * 64 + ch * 8);
      }
    }
    float sv[4][4];
#pragma unroll
    for (int ng = 0; ng < 4; ng++) {
      f32x4 sa = (f32x4){0.f, 0.f, 0.f, 0.f};
#pragma unroll
      for (int kk = 0; kk < 2; kk++) sa = MFMA16(qa[kk], kf[ng][kk], sa);
#pragma unroll
      for (int r = 0; r < 4; r++) sv[ng][r] = sa[r] * SCL + mreg[ng];
    }

    // online softmax (log2 domain); P -> swizzled per-wave LDS
    {
      float tm[4], alpha[4], ps[4];
#pragma unroll
      for (int r = 0; r < 4; r++)
        tm[r] = fmaxf(fmaxf(sv[0][r], sv[1][r]), fmaxf(sv[2][r], sv[3][r]));
#pragma unroll
      for (int m = 1; m < 16; m <<= 1)
#pragma unroll
        for (int r = 0; r < 4; r++) tm[r] = fmaxf(tm[r], __shfl_xor(tm[r], m));
#pragma unroll
      for (int r = 0; r < 4; r++) {
        float mn = fmaxf(mrow[r], tm[r]);
        alpha[r] = __builtin_amdgcn_exp2f(mrow[r] - mn);
        mrow[r] = mn;
        ps[r] = 0.0f;
      }
#pragma unroll
      for (int ng = 0; ng < 4; ng++)
#pragma unroll
        for (int r = 0; r < 4; r++) {
          float p = __builtin_amdgcn_exp2f(sv[ng][r] - mrow[r]);
          ps[r] += p;
          int prow = l4 * 4 + r, key = ng * 16 + l15;
          Pw[w][prow * 64 + (((key >> 3) ^ (prow & 7)) << 3) + (key & 7)] = f2bf(p);
        }
#pragma unroll
      for (int m = 1; m < 16; m <<= 1)
#pragma unroll
        for (int r = 0; r < 4; r++) ps[r] += __shfl_xor(ps[r], m);
#pragma unroll
      for (int r = 0; r < 4; r++) lrow[r] = lrow[r] * alpha[r] + ps[r];
#pragma unroll
      for (int ng = 0; ng < 4; ng++)
#pragma unroll
        for (int r = 0; r < 4; r++) oacc[ng][r] *= alpha[r];
    }

    // O += P V
    s16x8 vf[4][2];
#pragma unroll
    for (int ng = 0; ng < 4; ng++) {
      int row = ng * 16 + l15;
#pragma unroll
      for (int kk = 0; kk < 2; kk++) {
        int ch = (kk * 4 + l4) ^ (row & 7);
        vf[ng][kk] = *(const s16x8*)(Vt[cur] + row * 64 + ch * 8);
      }
    }
    s16x8 pf[2];
#pragma unroll
    for (int kk = 0; kk < 2; kk++) {
      int ch = (kk * 4 + l4) ^ (l15 & 7);
      pf[kk] = *(const s16x8*)(&Pw[w][0] + l15 * 64 + ch * 8);
    }
#pragma unroll
    for (int ng = 0; ng < 4; ng++)
#pragma unroll
      for (int kk = 0; kk < 2; kk++)
        oacc[ng] = MFMA16(pf[kk], vf[ng][kk], oacc[ng]);

    __syncthreads();  // drains next-tile staging; protects buffers
  }

  // epilogue: O[b,n,h*64+d] bf16
#pragma unroll
  for (int r = 0; r < 4; r++) {
    float rl = 1.0f / lrow[r];
#pragma unroll
    for (int ng = 0; ng < 4; ng++) {
      int n = qb * 64 + w * 16 + l4 * 4 + r;
      int d = ng * 16 + l15;
      O[(size_t)(b * 4096 + n) * 512 + h * 64 + d] = f2bf(oacc[ng][r] * rl);
    }
  }
}

extern "C" void kernel_launch(void* const* d_in, const int* in_sizes, int n_in,
                              void* d_out, int out_size, void* d_ws, size_t ws_size,
                              hipStream_t stream) {
  const float* keys     = (const float*)d_in[0];
  const float* values   = (const float*)d_in[1];
  const uint32_t* maskp = (const uint32_t*)d_in[2];
  const float* qk_gamma = (const float*)d_in[3];
  const float* qk_beta  = (const float*)d_in[4];
  const float* v_gamma  = (const float*)d_in[5];
  const float* v_beta   = (const float*)d_in[6];
  const float* W_qk     = (const float*)d_in[7];
  const float* W_v      = (const float*)d_in[8];
  const float* W_out    = (const float*)d_in[9];
  const float* b_out    = (const float*)d_in[10];
  float* out = (float*)d_out;
  char* ws = (char*)d_ws;
  const size_t MB = 1u << 20;
  short* kn    = (short*)(ws);
  short* vn    = (short*)(ws + 8 * MB);
  short* Qg    = (short*)(ws + 16 * MB);
  short* Kg    = (short*)(ws + 24 * MB);
  short* VTg   = (short*)(ws + 32 * MB);
  short* O     = (short*)(ws + 40 * MB);
  short* WqkT  = (short*)(ws + 48 * MB);
  short* WvT   = (short*)(ws + 49 * MB);
  short* WoutT = (short*)(ws + 49 * MB + 512 * 1024);
  float* mb    = (float*)(ws + 50 * MB);
  uint32_t* flag = (uint32_t*)(ws + 50 * MB + 32 * 1024);

  hipMemsetAsync(flag, 0, 4, stream);
  mask_detect_kernel<<<8, 256, 0, stream>>>(maskp, flag);
  mask_bias_kernel<<<32, 256, 0, stream>>>(maskp, flag, mb);
  transpose_kernel<<<dim3(32, 16), 256, 0, stream>>>(W_qk, WqkT, 512, 1024);
  transpose_kernel<<<dim3(16, 16), 256, 0, stream>>>(W_v, WvT, 512, 512);
  transpose_kernel<<<dim3(16, 16), 256, 0, stream>>>(W_out, WoutT, 512, 512);
  ln_kernel<<<dim3(8192, 2), 64, 0, stream>>>(keys, values, qk_gamma, qk_beta, v_gamma, v_beta, kn, vn);
  gemm_qk_kernel<<<dim3(64, 8), 256, 0, stream>>>(kn, WqkT, Qg, Kg);
  gemm_v_kernel<<<dim3(64, 4), 256, 0, stream>>>(vn, WvT, VTg);
  attn_kernel<<<dim3(64, 16), 256, 0, stream>>>(Qg, Kg, VTg, mb, O);
  gemm_out_kernel<<<dim3(64, 4), 256, 0, stream>>>(O, WoutT, b_out, out);
}

// Round 3
// 168.816 us; speedup vs baseline: 1.7602x; 1.6360x over previous
//
#include <hip/hip_runtime.h>
#include <stdint.h>

typedef float f32x4 __attribute__((ext_vector_type(4)));
typedef float f32x16 __attribute__((ext_vector_type(16)));
typedef short s16x8 __attribute__((ext_vector_type(8)));
typedef int i32x4 __attribute__((ext_vector_type(4)));

typedef const __attribute__((address_space(1))) uint32_t* gas_t;
typedef __attribute__((address_space(3))) uint32_t* las_t;

__device__ __forceinline__ void gload16(const void* g, void* l) {
  __builtin_amdgcn_global_load_lds((gas_t)g, (las_t)l, 16, 0, 0);
}

__device__ __forceinline__ short f2bf(float f) {
  union { float f; uint32_t u; } v; v.f = f;
  uint32_t r = v.u + 0x7fffu + ((v.u >> 16) & 1u);
  return (short)(r >> 16);
}

__device__ __forceinline__ uint32_t cvtpk_bf16(float lo, float hi) {
  uint32_t r;
  asm("v_cvt_pk_bf16_f32 %0, %1, %2" : "=v"(r) : "v"(lo), "v"(hi));
  return r;
}

// v_permlane32_swap_b32 a, b: a[32:63] <-> b[0:31]
// result: a = [a_lo, b_lo(moved up)], b = [a_hi(moved down), b_hi]
__device__ __forceinline__ void perm32swap(uint32_t& a, uint32_t& b) {
  asm("v_permlane32_swap_b32 %0, %1" : "+v"(a), "+v"(b));
}

#define MFMA16(a,b,c) __builtin_amdgcn_mfma_f32_16x16x32_bf16((a),(b),(c),0,0,0)
#define MFMA32(a,b,c) __builtin_amdgcn_mfma_f32_32x32x16_bf16((a),(b),(c),0,0,0)

// ---------------- mask handling (dtype-robust) ----------------
__global__ void mask_detect_kernel(const uint32_t* __restrict__ m, uint32_t* __restrict__ flag) {
  uint32_t v = m[blockIdx.x * 256 + threadIdx.x];
  if (v > 1u) atomicOr(flag, 1u);
}

__global__ void mask_bias_kernel(const uint32_t* __restrict__ m, const uint32_t* __restrict__ flag,
                                 float* __restrict__ mb) {
  int j = blockIdx.x * 256 + threadIdx.x;           // 8192
  uint32_t f = *flag;
  uint32_t v = f ? (uint32_t)((const uint8_t*)m)[j] : m[j];
  mb[j] = v ? -1e30f : 0.0f;
}

// ---------------- weight transpose f32 -> bf16 (WT[C][R]) ----------------
__global__ __launch_bounds__(256) void transpose_kernel(const float* __restrict__ W,
    short* __restrict__ WT, int R, int C) {
  __shared__ float tile[32][33];
  const int c0 = blockIdx.x * 32, r0 = blockIdx.y * 32;
  const int tx = threadIdx.x & 31, ty = threadIdx.x >> 5;
#pragma unroll
  for (int i = 0; i < 32; i += 8)
    tile[ty + i][tx] = W[(size_t)(r0 + ty + i) * C + c0 + tx];
  __syncthreads();
#pragma unroll
  for (int i = 0; i < 32; i += 8)
    WT[(size_t)(c0 + ty + i) * R + r0 + tx] = f2bf(tile[tx][ty + i]);
}

// ---------------- layernorm f32 -> bf16 ----------------
__global__ __launch_bounds__(64) void ln_kernel(const float* __restrict__ keys,
    const float* __restrict__ values, const float* __restrict__ g0, const float* __restrict__ b0,
    const float* __restrict__ g1, const float* __restrict__ b1,
    short* __restrict__ kn, short* __restrict__ vn) {
  const int row = blockIdx.x, sel = blockIdx.y, lane = threadIdx.x;
  const float* x = (sel ? values : keys) + (size_t)row * 512;
  const float* ga = sel ? g1 : g0;
  const float* be = sel ? b1 : b0;
  short* out = (sel ? vn : kn) + (size_t)row * 512;
  float4 a = ((const float4*)x)[lane * 2];
  float4 c = ((const float4*)x)[lane * 2 + 1];
  float s = a.x + a.y + a.z + a.w + c.x + c.y + c.z + c.w;
  float sq = a.x*a.x + a.y*a.y + a.z*a.z + a.w*a.w + c.x*c.x + c.y*c.y + c.z*c.z + c.w*c.w;
#pragma unroll
  for (int m = 1; m < 64; m <<= 1) { s += __shfl_xor(s, m); sq += __shfl_xor(sq, m); }
  float mu = s * (1.0f / 512.0f);
  float var = sq * (1.0f / 512.0f) - mu * mu;
  float rs = rsqrtf(var + 1e-5f);
  float xs[8] = {a.x, a.y, a.z, a.w, c.x, c.y, c.z, c.w};
  s16x8 o;
#pragma unroll
  for (int j = 0; j < 8; j++)
    o[j] = f2bf((xs[j] - mu) * rs * ga[lane * 8 + j] + be[lane * 8 + j]);
  *(s16x8*)(out + lane * 8) = o;
}

// ---------------- shared 128x128 GEMM core, K=512, BK=64 ----------------
__device__ __forceinline__ void gemm_core(const short* __restrict__ A,
                                          const short* __restrict__ BT,
                                          int row0, int col0,
                                          short* ldsA, short* ldsB,
                                          f32x4 acc[4][4]) {
  const int t = threadIdx.x;
  const int lane = t & 63, w = t >> 6;
  const int wr = w >> 1, wc = w & 1;
  const int l15 = lane & 15, l4 = lane >> 4;
#pragma unroll
  for (int mi = 0; mi < 4; mi++)
#pragma unroll
    for (int ni = 0; ni < 4; ni++) acc[mi][ni] = (f32x4){0.f, 0.f, 0.f, 0.f};

  for (int k0 = 0; k0 < 512; k0 += 64) {
    __syncthreads();
#pragma unroll
    for (int i = 0; i < 4; i++) {
      int q = i * 256 + t;               // chunk id: row=q>>3 (0..127), ch=q&7
      int row = q >> 3, ch = q & 7;
      int chs = ch ^ (row & 7);          // pre-swizzled source -> linear LDS is swizzled
      gload16(A + (size_t)(row0 + row) * 512 + k0 + chs * 8, ldsA + (i * 256 + w * 64) * 8);
      gload16(BT + (size_t)(col0 + row) * 512 + k0 + chs * 8, ldsB + (i * 256 + w * 64) * 8);
    }
    __syncthreads();
#pragma unroll
    for (int kk = 0; kk < 2; kk++) {
      s16x8 af[4], bf[4];
#pragma unroll
      for (int mi = 0; mi < 4; mi++) {
        int row = wr * 64 + mi * 16 + l15;
        int ch = (kk * 4 + l4) ^ (row & 7);
        af[mi] = *(const s16x8*)(ldsA + row * 64 + ch * 8);
      }
#pragma unroll
      for (int ni = 0; ni < 4; ni++) {
        int row = wc * 64 + ni * 16 + l15;
        int ch = (kk * 4 + l4) ^ (row & 7);
        bf[ni] = *(const s16x8*)(ldsB + row * 64 + ch * 8);
      }
#pragma unroll
      for (int mi = 0; mi < 4; mi++)
#pragma unroll
        for (int ni = 0; ni < 4; ni++)
          acc[mi][ni] = MFMA16(af[mi], bf[ni], acc[mi][ni]);
    }
  }
}

// GEMM1: kn @ W_qk -> Q (scale-folded), K in [B,H,N,64] bf16 with clip(+-5)
__global__ __launch_bounds__(256) void gemm_qk_kernel(const short* __restrict__ kn,
    const short* __restrict__ WqkT, short* __restrict__ Qg, short* __restrict__ Kg) {
  __shared__ short lds[2][128 * 64];
  f32x4 acc[4][4];
  const int bm = blockIdx.x, bn = blockIdx.y;
  gemm_core(kn, WqkT, bm * 128, bn * 128, lds[0], lds[1], acc);
  const int t = threadIdx.x, lane = t & 63, w = t >> 6, wr = w >> 1, wc = w & 1;
  const int l15 = lane & 15, l4 = lane >> 4;
  const float QSCL = 0.125f * 1.44269504088896f;   // fold softmax scale+log2e into Q
#pragma unroll
  for (int mi = 0; mi < 4; mi++)
#pragma unroll
    for (int ni = 0; ni < 4; ni++) {
      int col = bn * 128 + wc * 64 + ni * 16 + l15;
      bool isQ = (col < 512);
      short* dst = isQ ? Qg : Kg;
      int c = col & 511, h = c >> 6, d = c & 63;
#pragma unroll
      for (int r = 0; r < 4; r++) {
        int row = bm * 128 + wr * 64 + mi * 16 + l4 * 4 + r;
        int b = row >> 12, n = row & 4095;
        float v = acc[mi][ni][r];
        v = fminf(fmaxf(v, -5.0f), 5.0f);
        if (isQ) v *= QSCL;
        dst[((size_t)((b * 8 + h) * 4096 + n) << 6) + d] = f2bf(v);
      }
    }
}

// GEMM2: vn @ W_v -> VT [B,H,64,N] bf16 (transposed via swizzled LDS)
__global__ __launch_bounds__(256) void gemm_v_kernel(const short* __restrict__ vn,
    const short* __restrict__ WvT, short* __restrict__ VTg) {
  __shared__ short lds[2][128 * 64];
  f32x4 acc[4][4];
  const int bm = blockIdx.x, bn = blockIdx.y;
  gemm_core(vn, WvT, bm * 128, bn * 128, lds[0], lds[1], acc);
  __syncthreads();
  short* T = (short*)lds;
  const int t = threadIdx.x, lane = t & 63, w = t >> 6, wr = w >> 1, wc = w & 1;
  const int l15 = lane & 15, l4 = lane >> 4;
#pragma unroll
  for (int mi = 0; mi < 4; mi++)
#pragma unroll
    for (int ni = 0; ni < 4; ni++) {
      int c_loc = wc * 64 + ni * 16 + l15;
#pragma unroll
      for (int r = 0; r < 4; r++) {
        int n_loc = wr * 64 + mi * 16 + l4 * 4 + r;
        T[c_loc * 128 + (((n_loc >> 3) ^ (c_loc & 15)) << 3) + (n_loc & 7)] = f2bf(acc[mi][ni][r]);
      }
    }
  __syncthreads();
#pragma unroll
  for (int j = 0; j < 8; j++) {
    int c_loc = j * 16 + (t >> 4);
    int nch = t & 15;
    s16x8 v = *(const s16x8*)(T + c_loc * 128 + ((nch ^ (c_loc & 15)) << 3));
    int cg = bn * 128 + c_loc, h = cg >> 6, d = cg & 63;
    int rg = bm * 128 + nch * 8, b = rg >> 12;
    *(s16x8*)(VTg + (size_t)((b * 8 + h) * 64 + d) * 4096 + (rg & 4095)) = v;
  }
}

// GEMM3: O @ W_out + b -> f32 out
__global__ __launch_bounds__(256) void gemm_out_kernel(const short* __restrict__ O,
    const short* __restrict__ WoutT, const float* __restrict__ bias, float* __restrict__ out) {
  __shared__ short lds[2][128 * 64];
  f32x4 acc[4][4];
  const int bm = blockIdx.x, bn = blockIdx.y;
  gemm_core(O, WoutT, bm * 128, bn * 128, lds[0], lds[1], acc);
  const int t = threadIdx.x, lane = t & 63, w = t >> 6, wr = w >> 1, wc = w & 1;
  const int l15 = lane & 15, l4 = lane >> 4;
#pragma unroll
  for (int ni = 0; ni < 4; ni++) {
    int col = bn * 128 + wc * 64 + ni * 16 + l15;
    float bv = bias[col];
#pragma unroll
    for (int mi = 0; mi < 4; mi++)
#pragma unroll
      for (int r = 0; r < 4; r++) {
        int row = bm * 128 + wr * 64 + mi * 16 + l4 * 4 + r;
        out[(size_t)row * 512 + col] = acc[mi][ni][r] + bv;
      }
  }
}

// ---------------- flash attention (R3: 32x32 swapped-QK, in-register softmax) ----
// grid 256 blocks x 512 threads. 8 waves, QBLK=32/wave (BQ=256), KVBLK=64.
// S^T = mfma(K, Q): lane owns q-row (col=lane&31); softmax lane-local.
// P -> bf16 via cvt_pk + permlane32_swap; O^T = mfma(V^T, P^T) keeps col=q.
__global__ __launch_bounds__(512) void attn_kernel(const short* __restrict__ Qg,
    const short* __restrict__ Kg, const short* __restrict__ VTg,
    const float* __restrict__ mb, short* __restrict__ O) {
  __shared__ short smem[16640];   // Kt[2][4096] | Vt[2][4096] | mbs[2][64] f32
  short* KtB = smem;
  short* VtB = smem + 8192;
  float* mbsB = (float*)(smem + 16384);

  const int bid = blockIdx.x;                 // 0..255
  const int xcd = bid & 7, local = bid >> 3;
  const int bh = xcd * 2 + (local & 1);       // 2 bh per XCD -> K/V L2-resident
  const int qb = local >> 1;                  // 0..15
  const int b = bh >> 3, h = bh & 7;
  const int t = threadIdx.x, lane = t & 63, w = t >> 6;
  const int l31 = lane & 31, hh = lane >> 5;

  const short* Qp = Qg + (size_t)bh * 4096 * 64;
  const short* Kp = Kg + (size_t)bh * 4096 * 64;
  const short* Vp = VTg + (size_t)bh * 64 * 4096;
  const float* mbp = mb + b * 4096;

  // Q fragments (B-operand): lane holds Q[qrow][dblk*16 + hh*8 .. +8], scale pre-folded
  const int qrow = qb * 256 + w * 32 + l31;
  s16x8 qf[4];
#pragma unroll
  for (int dblk = 0; dblk < 4; dblk++)
    qf[dblk] = *(const s16x8*)(Qp + (size_t)qrow * 64 + dblk * 16 + hh * 8);

  f32x16 oac[2];
#pragma unroll
  for (int db = 0; db < 2; db++)
#pragma unroll
    for (int r = 0; r < 16; r++) oac[db][r] = 0.0f;
  float m_ = -60.0f, l_ = 0.0f;

  auto STAGE = [&](int buf, int kt) {
    int row = t >> 3, ch = t & 7, chs = ch ^ (row & 7);
    gload16(Kp + (size_t)(kt * 64 + row) * 64 + chs * 8, KtB + buf * 4096 + w * 512);
    gload16(Vp + (size_t)row * 4096 + kt * 64 + chs * 8, VtB + buf * 4096 + w * 512);
    if (t < 16) gload16(mbp + kt * 64 + lane * 4, mbsB + buf * 64);
  };

  STAGE(0, 0);
  __syncthreads();

  for (int kt = 0; kt < 64; kt++) {
    const int cur = kt & 1;
    if (kt < 63) STAGE(cur ^ 1, kt + 1);
    const short* Kt = KtB + cur * 4096;
    const short* Vt = VtB + cur * 4096;
    const float* mbs = mbsB + cur * 64;

    // S^T = K . Q^T  (A=K frag: row k=lane&31, d-slice; B=Q frag)
    f32x16 sc[2];
    __builtin_amdgcn_s_setprio(1);
#pragma unroll
    for (int kb = 0; kb < 2; kb++) {
      f32x16 s_;
#pragma unroll
      for (int r = 0; r < 16; r++) s_[r] = 0.0f;
      const int krow = kb * 32 + l31;
#pragma unroll
      for (int dblk = 0; dblk < 4; dblk++) {
        int ch = (2 * dblk + hh) ^ (krow & 7);
        s16x8 kf = *(const s16x8*)(Kt + krow * 64 + ch * 8);
        s_ = MFMA32(kf, qf[dblk], s_);
      }
      sc[kb] = s_;
    }
    __builtin_amdgcn_s_setprio(0);

    // bias + running max (per-lane q-row; only xor-32 crosses lanes)
    float mx = -1e30f;
#pragma unroll
    for (int kb = 0; kb < 2; kb++) {
#pragma unroll
      for (int g = 0; g < 4; g++) {
        f32x4 bv = *(const f32x4*)(mbs + kb * 32 + g * 8 + hh * 4);
#pragma unroll
        for (int c = 0; c < 4; c++) {
          float s = sc[kb][g * 4 + c] + bv[c];
          sc[kb][g * 4 + c] = s;
          mx = fmaxf(mx, s);
        }
      }
    }
    mx = fmaxf(mx, __shfl_xor(mx, 32));
    float mnew = fmaxf(m_, mx);
    float alpha = __builtin_amdgcn_exp2f(m_ - mnew);
    m_ = mnew;

    // P = exp2(S - m); pack to bf16 A-layout via cvt_pk + permlane32_swap
    float ls = 0.0f;
    uint32_t pw[4][4];
#pragma unroll
    for (int kb = 0; kb < 2; kb++) {
      float p[16];
#pragma unroll
      for (int r = 0; r < 16; r++) {
        p[r] = __builtin_amdgcn_exp2f(sc[kb][r] - m_);
        ls += p[r];
      }
#pragma unroll
      for (int ksl = 0; ksl < 2; ksl++) {
        const int fi = kb * 2 + ksl, b0 = ksl * 8;
        uint32_t a0 = cvtpk_bf16(p[b0 + 0], p[b0 + 1]);
        uint32_t b0w = cvtpk_bf16(p[b0 + 4], p[b0 + 5]);
        perm32swap(a0, b0w);                 // a0 -> w0, b0w -> w2
        uint32_t a1 = cvtpk_bf16(p[b0 + 2], p[b0 + 3]);
        uint32_t b1w = cvtpk_bf16(p[b0 + 6], p[b0 + 7]);
        perm32swap(a1, b1w);                 // a1 -> w1, b1w -> w3
        pw[fi][0] = a0; pw[fi][1] = a1; pw[fi][2] = b0w; pw[fi][3] = b1w;
      }
    }
    ls += __shfl_xor(ls, 32);
    l_ = l_ * alpha + ls;
#pragma unroll
    for (int db = 0; db < 2; db++)
#pragma unroll
      for (int r = 0; r < 16; r++) oac[db][r] *= alpha;

    // O^T += V^T . P^T   (A=V^T frag: row d, k-slice; B=P frag)
    __builtin_amdgcn_s_setprio(1);
#pragma unroll
    for (int db = 0; db < 2; db++) {
      const int d = db * 32 + l31;
#pragma unroll
      for (int ks = 0; ks < 4; ks++) {
        int ch = (2 * ks + hh) ^ (d & 7);
        s16x8 vf = *(const s16x8*)(Vt + d * 64 + ch * 8);
        i32x4 pv = {(int)pw[ks][0], (int)pw[ks][1], (int)pw[ks][2], (int)pw[ks][3]};
        oac[db] = MFMA32(vf, __builtin_bit_cast(s16x8, pv), oac[db]);
      }
    }
    __builtin_amdgcn_s_setprio(0);

    __syncthreads();   // next-tile staging complete; all waves done with cur
  }

  // epilogue: normalize, transpose via per-wave LDS region, coalesced store
  float inv = 1.0f / l_;
  short* reg16 = smem + w * 2048;            // 4KB per wave (reuses K/V space)
#pragma unroll
  for (int db = 0; db < 2; db++)
#pragma unroll
    for (int g = 0; g < 4; g++) {
      uint32_t w0 = cvtpk_bf16(oac[db][g * 4 + 0] * inv, oac[db][g * 4 + 1] * inv);
      uint32_t w1 = cvtpk_bf16(oac[db][g * 4 + 2] * inv, oac[db][g * 4 + 3] * inv);
      int chunk = db * 4 + g;
      // byte addr: q*128 + (chunk^(q&7))*16 + hh*8
      uint2* dst = (uint2*)((char*)reg16 + l31 * 128 + ((chunk ^ (l31 & 7)) << 4) + hh * 8);
      *dst = make_uint2(w0, w1);
    }
#pragma unroll
  for (int i = 0; i < 4; i++) {
    int c = hh * 4 + i;
    s16x8 v = *(const s16x8*)((char*)reg16 + l31 * 128 + ((c ^ (l31 & 7)) << 4));
    *(s16x8*)(O + ((size_t)(b * 4096 + qrow) * 512) + h * 64 + c * 8) = v;
  }
}

extern "C" void kernel_launch(void* const* d_in, const int* in_sizes, int n_in,
                              void* d_out, int out_size, void* d_ws, size_t ws_size,
                              hipStream_t stream) {
  const float* keys     = (const float*)d_in[0];
  const float* values   = (const float*)d_in[1];
  const uint32_t* maskp = (const uint32_t*)d_in[2];
  const float* qk_gamma = (const float*)d_in[3];
  const float* qk_beta  = (const float*)d_in[4];
  const float* v_gamma  = (const float*)d_in[5];
  const float* v_beta   = (const float*)d_in[6];
  const float* W_qk     = (const float*)d_in[7];
  const float* W_v      = (const float*)d_in[8];
  const float* W_out    = (const float*)d_in[9];
  const float* b_out    = (const float*)d_in[10];
  float* out = (float*)d_out;
  char* ws = (char*)d_ws;
  const size_t MB = 1u << 20;
  short* kn    = (short*)(ws);
  short* vn    = (short*)(ws + 8 * MB);
  short* Qg    = (short*)(ws + 16 * MB);
  short* Kg    = (short*)(ws + 24 * MB);
  short* VTg   = (short*)(ws + 32 * MB);
  short* O     = (short*)(ws + 40 * MB);
  short* WqkT  = (short*)(ws + 48 * MB);
  short* WvT   = (short*)(ws + 49 * MB);
  short* WoutT = (short*)(ws + 49 * MB + 512 * 1024);
  float* mb    = (float*)(ws + 50 * MB);
  uint32_t* flag = (uint32_t*)(ws + 50 * MB + 32 * 1024);

  hipMemsetAsync(flag, 0, 4, stream);
  mask_detect_kernel<<<8, 256, 0, stream>>>(maskp, flag);
  mask_bias_kernel<<<32, 256, 0, stream>>>(maskp, flag, mb);
  transpose_kernel<<<dim3(32, 16), 256, 0, stream>>>(W_qk, WqkT, 512, 1024);
  transpose_kernel<<<dim3(16, 16), 256, 0, stream>>>(W_v, WvT, 512, 512);
  transpose_kernel<<<dim3(16, 16), 256, 0, stream>>>(W_out, WoutT, 512, 512);
  ln_kernel<<<dim3(8192, 2), 64, 0, stream>>>(keys, values, qk_gamma, qk_beta, v_gamma, v_beta, kn, vn);
  gemm_qk_kernel<<<dim3(64, 8), 256, 0, stream>>>(kn, WqkT, Qg, Kg);
  gemm_v_kernel<<<dim3(64, 4), 256, 0, stream>>>(vn, WvT, VTg);
  attn_kernel<<<256, 512, 0, stream>>>(Qg, Kg, VTg, mb, O);
  gemm_out_kernel<<<dim3(64, 4), 256, 0, stream>>>(O, WoutT, b_out, out);
}